// Round 10
// baseline (268.318 us; speedup 1.0000x reference)
//
#include <hip/hip_runtime.h>
#include <cmath>

#define BATCH 8
#define SEQLEN 4096
#define DMODEL 192
#define DINNER 384
#define DSTATE 16
#define DTRANK 12
#define XSTR 64            // padded x_dbl row stride (44 real cols)
#define MTOT (BATCH*SEQLEN)
#define CH 32              // scan chunk length
#define NC (SEQLEN/CH)     // 128 chunks

typedef __bf16 bf16x8 __attribute__((ext_vector_type(8)));
typedef float f32x4 __attribute__((ext_vector_type(4)));
typedef unsigned short us8 __attribute__((ext_vector_type(8)));

__device__ __forceinline__ float fast_rcp(float x) { return __builtin_amdgcn_rcpf(x); }
__device__ __forceinline__ float silu_f(float x) { return x * fast_rcp(1.f + __expf(-x)); }
__device__ __forceinline__ unsigned short f2bf(float f) {
  unsigned u = __float_as_uint(f);
  return (unsigned short)((u + 0x7FFF + ((u >> 16) & 1)) >> 16);   // RNE
}
__device__ __forceinline__ float bf2f(unsigned short b) {
  return __uint_as_float(((unsigned)b) << 16);
}

// a[n] = e1^(n+1), binary tree, depth 4
#define POW16(a, e1)                                                        \
  a[0] = (e1); a[1] = (e1) * (e1); a[2] = a[1] * (e1); a[3] = a[1] * a[1];  \
  a[4] = a[3] * (e1); a[5] = a[3] * a[1]; a[6] = a[3] * a[2];               \
  a[7] = a[3] * a[3]; a[8] = a[7] * (e1); a[9] = a[7] * a[1];               \
  a[10] = a[7] * a[2]; a[11] = a[7] * a[3]; a[12] = a[7] * a[4];            \
  a[13] = a[7] * a[5]; a[14] = a[7] * a[6]; a[15] = a[7] * a[7];

// softplus pieces: dtv = softplus(s), e1 = exp(-dtv) = sigmoid(-s) via rcp
#define SOFTPLUS_E1(s, dtv, e1)                                             \
  { const float w_ = __expf(-fabsf(s));                                     \
    const float t_ = 1.f + w_;                                              \
    const float rq_ = fast_rcp(t_);                                         \
    dtv = fmaxf(s, 0.f) + __logf(t_);                                       \
    e1 = ((s) > 0.f) ? w_ * rq_ : rq_; }

// 12-term dot vs LDS row (float4 reads, 3-way split)
__device__ __forceinline__ float dot12(const float* __restrict__ Lr,
                                       const float* __restrict__ wr, float b2) {
  float4 x0 = *(const float4*)(Lr);
  float4 x1 = *(const float4*)(Lr + 4);
  float4 x2 = *(const float4*)(Lr + 8);
  float sA = fmaf(x0.x, wr[0], b2);
  sA = fmaf(x0.y, wr[1], sA); sA = fmaf(x0.z, wr[2], sA); sA = fmaf(x0.w, wr[3], sA);
  float sB = x1.x * wr[4];
  sB = fmaf(x1.y, wr[5], sB); sB = fmaf(x1.z, wr[6], sB); sB = fmaf(x1.w, wr[7], sB);
  float sC = x2.x * wr[8];
  sC = fmaf(x2.y, wr[9], sC); sC = fmaf(x2.z, wr[10], sC); sC = fmaf(x2.w, wr[11], sC);
  return sA + (sB + sC);
}

// single prep kernel: cast in_proj_w, pad+cast x_proj_w, cast out_proj_w
__global__ __launch_bounds__(256) void prep_k(const float* __restrict__ in_w,
                                              const float* __restrict__ xw,
                                              const float* __restrict__ ow,
                                              unsigned short* __restrict__ wb,
                                              unsigned short* __restrict__ wxb,
                                              unsigned short* __restrict__ owb) {
  const int i = blockIdx.x * 256 + threadIdx.x;
  if (i < 768 * DMODEL) wb[i] = f2bf(in_w[i]);
  if (i < XSTR * DINNER) wxb[i] = (i < 44 * DINNER) ? f2bf(xw[i]) : (unsigned short)0;
  if (i < DMODEL * DINNER) owb[i] = f2bf(ow[i]);
}

// in_proj: [M][768] = hs[M][192] @ in_w^T. BM=128 BN=128 BK=32, XCD-chunked swizzle.
__global__ __launch_bounds__(256) void gemm_in(const float* __restrict__ hs,
                                               const unsigned short* __restrict__ wb,
                                               unsigned short* __restrict__ xb,
                                               unsigned short* __restrict__ zb) {
  __shared__ unsigned short Als[128 * 40];   // 80B rows
  __shared__ unsigned short Bls[128 * 40];
  const int tid = threadIdx.x;
  const int bid = blockIdx.y * 6 + blockIdx.x;        // 0..1535
  const int lid = (bid & 7) * 192 + (bid >> 3);       // bijective (1536%8==0)
  const int m0 = (lid / 6) * 128, n0 = (lid % 6) * 128;
  const int w = tid >> 6, l = tid & 63;
  const int wm = (w >> 1) * 64, wn = (w & 1) * 64;
  const int lr = l & 15, lk8 = (l >> 4) * 8;
  const int ar = tid >> 1, ag = (tid & 1) * 16;
  const float* Ap = hs + (size_t)(m0 + ar) * DMODEL + ag;
  const unsigned short* Wp = wb + (size_t)(n0 + ar) * DMODEL + ag;
  f32x4 acc[4][4];
#pragma unroll
  for (int i = 0; i < 4; i++)
#pragma unroll
    for (int j = 0; j < 4; j++) acc[i][j] = (f32x4){0.f, 0.f, 0.f, 0.f};
#pragma unroll
  for (int k0 = 0; k0 < DMODEL; k0 += 32) {
    float4 f0 = *(const float4*)(Ap + k0);
    float4 f1 = *(const float4*)(Ap + k0 + 4);
    float4 f2 = *(const float4*)(Ap + k0 + 8);
    float4 f3 = *(const float4*)(Ap + k0 + 12);
    us8 b0 = *(const us8*)(Wp + k0);
    us8 b1 = *(const us8*)(Wp + k0 + 8);
    us8 a0, a1;
    a0[0] = f2bf(f0.x); a0[1] = f2bf(f0.y); a0[2] = f2bf(f0.z); a0[3] = f2bf(f0.w);
    a0[4] = f2bf(f1.x); a0[5] = f2bf(f1.y); a0[6] = f2bf(f1.z); a0[7] = f2bf(f1.w);
    a1[0] = f2bf(f2.x); a1[1] = f2bf(f2.y); a1[2] = f2bf(f2.z); a1[3] = f2bf(f2.w);
    a1[4] = f2bf(f3.x); a1[5] = f2bf(f3.y); a1[6] = f2bf(f3.z); a1[7] = f2bf(f3.w);
    __syncthreads();
    *(us8*)(&Als[ar * 40 + ag]) = a0;
    *(us8*)(&Als[ar * 40 + ag + 8]) = a1;
    *(us8*)(&Bls[ar * 40 + ag]) = b0;
    *(us8*)(&Bls[ar * 40 + ag + 8]) = b1;
    __syncthreads();
    bf16x8 bfr[4];
#pragma unroll
    for (int fn = 0; fn < 4; fn++)
      bfr[fn] = *(const bf16x8*)(&Bls[(wn + fn * 16 + lr) * 40 + lk8]);
#pragma unroll
    for (int fm = 0; fm < 4; fm++) {
      bf16x8 af = *(const bf16x8*)(&Als[(wm + fm * 16 + lr) * 40 + lk8]);
#pragma unroll
      for (int fn = 0; fn < 4; fn++)
        acc[fm][fn] = __builtin_amdgcn_mfma_f32_16x16x32_bf16(af, bfr[fn], acc[fm][fn], 0, 0, 0);
    }
  }
  const int r0 = (l >> 4) * 4;   // C/D: col=lane&15, row=(lane>>4)*4+reg
  unsigned short* dst = (n0 < DINNER) ? xb : zb;
  const int cb0 = (n0 < DINNER) ? n0 : (n0 - DINNER);
#pragma unroll
  for (int fm = 0; fm < 4; fm++) {
    const size_t rowb = (size_t)(m0 + wm + fm * 16 + r0);
#pragma unroll
    for (int fn = 0; fn < 4; fn++) {
      const int col = cb0 + wn + fn * 16 + lr;
#pragma unroll
      for (int r = 0; r < 4; r++)
        dst[(rowb + r) * DINNER + col] = f2bf(acc[fm][fn][r]);
    }
  }
}

// x_proj with FUSED depthwise conv+SiLU in the A-staging (each u element is
// staged exactly once -> conv kernel eliminated; u16 written through here).
__global__ __launch_bounds__(256) void xproj_conv(const unsigned short* __restrict__ xb,
                                                  const float* __restrict__ cw,
                                                  const float* __restrict__ cb,
                                                  const unsigned short* __restrict__ wxb,
                                                  float* __restrict__ xdbl,
                                                  unsigned short* __restrict__ u16) {
  __shared__ unsigned short Als[64 * 40];
  __shared__ unsigned short Bls[64 * 40];
  __shared__ float cws[DINNER * 4];   // [0..3*384) = cw, [3*384..) = cb
  const int tid = threadIdx.x;
  const int m0 = blockIdx.x * 64;
  for (int i = tid; i < DINNER * 4; i += 256)
    cws[i] = (i < DINNER * 3) ? cw[i] : cb[i - DINNER * 3];
  const int w = tid >> 6, l = tid & 63;
  const int wm = (w >> 1) * 32, wn = (w & 1) * 32;
  const int lr = l & 15, lk8 = (l >> 4) * 8;
  const int ar = tid >> 2, ag = (tid & 3) * 8;
  const int m = m0 + ar;
  const int lpos = m % SEQLEN;
  const bool hm = (lpos > 0), hp = (lpos < SEQLEN - 1);
  const unsigned short* Ap = xb + (size_t)m * DINNER + ag;
  const unsigned short* Wp = wxb + (size_t)ar * DINNER + ag;
  f32x4 acc[2][2];
#pragma unroll
  for (int i = 0; i < 2; i++)
#pragma unroll
    for (int j = 0; j < 2; j++) acc[i][j] = (f32x4){0.f, 0.f, 0.f, 0.f};
  __syncthreads();   // cws ready
#pragma unroll
  for (int k0 = 0; k0 < DINNER; k0 += 32) {
    us8 c0 = *(const us8*)(Ap + k0);
    us8 cm = c0, cp = c0;
    if (hm) cm = *(const us8*)(Ap + k0 - DINNER);
    if (hp) cp = *(const us8*)(Ap + k0 + DINNER);
    us8 b0 = *(const us8*)(Wp + k0);
    us8 a0;
#pragma unroll
    for (int j = 0; j < 8; j++) {
      const int col = ag + k0 + j;
      float s = cws[DINNER * 3 + col] + cws[col * 3 + 1] * bf2f(c0[j]);
      if (hm) s += cws[col * 3 + 0] * bf2f(cm[j]);
      if (hp) s += cws[col * 3 + 2] * bf2f(cp[j]);
      a0[j] = f2bf(silu_f(s));
    }
    *(us8*)(u16 + (size_t)m * DINNER + ag + k0) = a0;   // write-through for scans
    __syncthreads();
    *(us8*)(&Als[ar * 40 + ag]) = a0;
    *(us8*)(&Bls[ar * 40 + ag]) = b0;
    __syncthreads();
    bf16x8 bf0 = *(const bf16x8*)(&Bls[(wn + lr) * 40 + lk8]);
    bf16x8 bf1 = *(const bf16x8*)(&Bls[(wn + 16 + lr) * 40 + lk8]);
#pragma unroll
    for (int fm = 0; fm < 2; fm++) {
      bf16x8 af = *(const bf16x8*)(&Als[(wm + fm * 16 + lr) * 40 + lk8]);
      acc[fm][0] = __builtin_amdgcn_mfma_f32_16x16x32_bf16(af, bf0, acc[fm][0], 0, 0, 0);
      acc[fm][1] = __builtin_amdgcn_mfma_f32_16x16x32_bf16(af, bf1, acc[fm][1], 0, 0, 0);
    }
  }
  const int r0 = (l >> 4) * 4;
#pragma unroll
  for (int fm = 0; fm < 2; fm++) {
    const size_t rowb = (size_t)(m0 + wm + fm * 16 + r0);
#pragma unroll
    for (int fn = 0; fn < 2; fn++) {
      const int col = wn + fn * 16 + lr;
#pragma unroll
      for (int r = 0; r < 4; r++)
        xdbl[(rowb + r) * XSTR + col] = acc[fm][fn][r];
    }
  }
}

// ---- chunked parallel scan, thread-per-(b,d), 16 states in registers ----
// dt fused; GROUP-OF-8 software pipeline: phase A computes 8 independent
// dots + softplus (+ u/z loads) so transcendental latencies overlap; phase B
// runs 8 recurrence steps with zero transcendentals / zero global loads.
__global__ __launch_bounds__(384, 4) void scan_part1(const unsigned short* __restrict__ u16,
                                                     const float* __restrict__ xdbl,
                                                     const float* __restrict__ A_log,
                                                     const float* __restrict__ dtw,
                                                     const float* __restrict__ dtb,
                                                     float* __restrict__ Pbuf,
                                                     float* __restrict__ Sbuf) {
  __shared__ float XL[CH * 32];               // [l][0..11]=dt-cols, [l][12..27]=B
  const int d = threadIdx.x;
  const int c = blockIdx.x, b = blockIdx.y;
  const size_t mbase = (size_t)b * SEQLEN + (size_t)c * CH;
  if (d < CH * 7) {
    const int r = d / 7, q = d % 7;
    float4 v = *(const float4*)(xdbl + (mbase + r) * XSTR + q * 4);
    *(float4*)(&XL[r * 32 + q * 4]) = v;
  }
  float wr[DTRANK];
#pragma unroll
  for (int q = 0; q < 3; q++)
    *(float4*)(wr + q * 4) = *(const float4*)(dtw + d * DTRANK + q * 4);
  const float b2 = 2.f * dtb[d];
  bool fastp = true;
#pragma unroll
  for (int n = 0; n < DSTATE; n++)
    fastp = fastp && (fabsf(A_log[d * DSTATE + n] - __logf((float)(n + 1))) < 1e-5f);
  float h[DSTATE];
#pragma unroll
  for (int n = 0; n < DSTATE; n++) h[n] = 0.f;
  __syncthreads();
  float P[DSTATE];
  if (fastp) {
    float Pprod = 1.f;
    for (int g = 0; g < CH / 8; g++) {
      float e18[8], du8[8];
#pragma unroll
      for (int j = 0; j < 8; j++) {                 // phase A: independent
        const int l = g * 8 + j;
        const float s = dot12(&XL[l * 32], wr, b2);
        const float uvj = bf2f(u16[(mbase + l) * DINNER + d]);
        float dtv, e1;
        SOFTPLUS_E1(s, dtv, e1)
        e18[j] = e1;
        du8[j] = dtv * uvj;
      }
      Pprod *= ((e18[0] * e18[1]) * (e18[2] * e18[3])) *
               ((e18[4] * e18[5]) * (e18[6] * e18[7]));
#pragma unroll
      for (int j = 0; j < 8; j++) {                 // phase B: recurrence
        const int l = g * 8 + j;
        const float* Lr = &XL[l * 32 + 12];
        float4 B0 = *(const float4*)(Lr);
        float4 B1 = *(const float4*)(Lr + 4);
        float4 B2 = *(const float4*)(Lr + 8);
        float4 B3 = *(const float4*)(Lr + 12);
        float a[DSTATE];
        POW16(a, e18[j])
        const float du = du8[j];
        h[0]  = fmaf(a[0],  h[0],  du * B0.x); h[1]  = fmaf(a[1],  h[1],  du * B0.y);
        h[2]  = fmaf(a[2],  h[2],  du * B0.z); h[3]  = fmaf(a[3],  h[3],  du * B0.w);
        h[4]  = fmaf(a[4],  h[4],  du * B1.x); h[5]  = fmaf(a[5],  h[5],  du * B1.y);
        h[6]  = fmaf(a[6],  h[6],  du * B1.z); h[7]  = fmaf(a[7],  h[7],  du * B1.w);
        h[8]  = fmaf(a[8],  h[8],  du * B2.x); h[9]  = fmaf(a[9],  h[9],  du * B2.y);
        h[10] = fmaf(a[10], h[10], du * B2.z); h[11] = fmaf(a[11], h[11], du * B2.w);
        h[12] = fmaf(a[12], h[12], du * B3.x); h[13] = fmaf(a[13], h[13], du * B3.y);
        h[14] = fmaf(a[14], h[14], du * B3.z); h[15] = fmaf(a[15], h[15], du * B3.w);
      }
    }
    POW16(P, Pprod)
  } else {
    float Av[DSTATE];
#pragma unroll
    for (int n = 0; n < DSTATE; n++) Av[n] = -__expf(A_log[d * DSTATE + n]);
    float dtsum = 0.f;
    for (int l = 0; l < CH; l++) {
      const float uv = bf2f(u16[(mbase + l) * DINNER + d]);
      const float* Lr = &XL[l * 32];
      const float s = dot12(Lr, wr, b2);
      float dtv, e1;
      SOFTPLUS_E1(s, dtv, e1)
      (void)e1;
      const float du = dtv * uv;
      dtsum += dtv;
#pragma unroll
      for (int n = 0; n < DSTATE; n++)
        h[n] = fmaf(__expf(dtv * Av[n]), h[n], du * Lr[12 + n]);
    }
#pragma unroll
    for (int n = 0; n < DSTATE; n++) P[n] = __expf(dtsum * Av[n]);
  }
  float* Pp = Pbuf + ((size_t)(b * NC + c) * DINNER + d) * DSTATE;
  float* Sp = Sbuf + ((size_t)(b * NC + c) * DINNER + d) * DSTATE;
#pragma unroll
  for (int q = 0; q < 4; q++) {
    float4 pv, sv;
    pv.x = P[q * 4 + 0]; pv.y = P[q * 4 + 1]; pv.z = P[q * 4 + 2]; pv.w = P[q * 4 + 3];
    sv.x = h[q * 4 + 0]; sv.y = h[q * 4 + 1]; sv.z = h[q * 4 + 2]; sv.w = h[q * 4 + 3];
    *(float4*)(Pp + q * 4) = pv;
    *(float4*)(Sp + q * 4) = sv;
  }
}

// Pass 2: combine across chunks, unroll x8 with batched loads.
__global__ __launch_bounds__(256) void scan_part2(float* __restrict__ Pbuf,
                                                  const float* __restrict__ Sbuf) {
  const int i = blockIdx.x * 256 + threadIdx.x;
  const int b = i / (DINNER * DSTATE);
  const int r = i % (DINNER * DSTATE);
  const size_t cs = DINNER * DSTATE;
  const size_t base = (size_t)b * NC * cs + r;
  float h = 0.f;
  for (int c0 = 0; c0 < NC; c0 += 8) {
    float pp[8], ss[8];
#pragma unroll
    for (int j = 0; j < 8; j++) {
      pp[j] = Pbuf[base + (size_t)(c0 + j) * cs];
      ss[j] = Sbuf[base + (size_t)(c0 + j) * cs];
    }
#pragma unroll
    for (int j = 0; j < 8; j++) {
      Pbuf[base + (size_t)(c0 + j) * cs] = h;
      h = fmaf(pp[j], h, ss[j]);
    }
  }
}

// Pass 3: re-run from h0, grouped pipeline; y = (h.C + D*u)*silu(z) -> bf16.
__global__ __launch_bounds__(384, 4) void scan_part3(const unsigned short* __restrict__ u16,
                                                     const float* __restrict__ xdbl,
                                                     const float* __restrict__ A_log,
                                                     const float* __restrict__ dtw,
                                                     const float* __restrict__ dtb,
                                                     const float* __restrict__ Dsk,
                                                     const unsigned short* __restrict__ zb,
                                                     const float* __restrict__ H0,
                                                     unsigned short* __restrict__ yb) {
  __shared__ float XL[CH * 48];   // [l][0..11]=dt-cols, [12..27]=B, [28..43]=C
  const int d = threadIdx.x;
  const int c = blockIdx.x, b = blockIdx.y;
  const size_t mbase = (size_t)b * SEQLEN + (size_t)c * CH;
  if (d < CH * 11) {
    const int r = d / 11, q = d % 11;
    float4 v = *(const float4*)(xdbl + (mbase + r) * XSTR + q * 4);
    *(float4*)(&XL[r * 48 + q * 4]) = v;
  }
  float wr[DTRANK];
#pragma unroll
  for (int q = 0; q < 3; q++)
    *(float4*)(wr + q * 4) = *(const float4*)(dtw + d * DTRANK + q * 4);
  const float b2 = 2.f * dtb[d];
  bool fastp = true;
#pragma unroll
  for (int n = 0; n < DSTATE; n++)
    fastp = fastp && (fabsf(A_log[d * DSTATE + n] - __logf((float)(n + 1))) < 1e-5f);
  const float Dv = Dsk[d];
  float h[DSTATE];
  {
    const float* Hp = H0 + ((size_t)(b * NC + c) * DINNER + d) * DSTATE;
#pragma unroll
    for (int q = 0; q < 4; q++) {
      float4 v = *(const float4*)(Hp + q * 4);
      h[q * 4 + 0] = v.x; h[q * 4 + 1] = v.y; h[q * 4 + 2] = v.z; h[q * 4 + 3] = v.w;
    }
  }
  __syncthreads();
  if (fastp) {
    for (int g = 0; g < CH / 8; g++) {
      float e18[8], du8[8], uD8[8], sz8[8];
#pragma unroll
      for (int j = 0; j < 8; j++) {                 // phase A: independent
        const int l = g * 8 + j;
        const float s = dot12(&XL[l * 48], wr, b2);
        const float uvj = bf2f(u16[(mbase + l) * DINNER + d]);
        const float zvj = bf2f(zb[(mbase + l) * DINNER + d]);
        float dtv, e1;
        SOFTPLUS_E1(s, dtv, e1)
        e18[j] = e1;
        du8[j] = dtv * uvj;
        uD8[j] = Dv * uvj;
        sz8[j] = silu_f(zvj);
      }
#pragma unroll
      for (int j = 0; j < 8; j++) {                 // phase B: recurrence
        const int l = g * 8 + j;
        const float* Lr = &XL[l * 48 + 12];
        float4 B0 = *(const float4*)(Lr);
        float4 B1 = *(const float4*)(Lr + 4);
        float4 B2 = *(const float4*)(Lr + 8);
        float4 B3 = *(const float4*)(Lr + 12);
        float4 C0 = *(const float4*)(Lr + 16);
        float4 C1 = *(const float4*)(Lr + 20);
        float4 C2 = *(const float4*)(Lr + 24);
        float4 C3 = *(const float4*)(Lr + 28);
        float a[DSTATE];
        POW16(a, e18[j])
        const float du = du8[j];
        float y0 = uD8[j], y1 = 0.f, y2 = 0.f, y3 = 0.f;
        h[0]  = fmaf(a[0],  h[0],  du * B0.x); y0 = fmaf(h[0],  C0.x, y0);
        h[1]  = fmaf(a[1],  h[1],  du * B0.y); y1 = fmaf(h[1],  C0.y, y1);
        h[2]  = fmaf(a[2],  h[2],  du * B0.z); y2 = fmaf(h[2],  C0.z, y2);
        h[3]  = fmaf(a[3],  h[3],  du * B0.w); y3 = fmaf(h[3],  C0.w, y3);
        h[4]  = fmaf(a[4],  h[4],  du * B1.x); y0 = fmaf(h[4],  C1.x, y0);
        h[5]  = fmaf(a[5],  h[5],  du * B1.y); y1 = fmaf(h[5],  C1.y, y1);
        h[6]  = fmaf(a[6],  h[6],  du * B1.z); y2 = fmaf(h[6],  C1.z, y2);
        h[7]  = fmaf(a[7],  h[7],  du * B1.w); y3 = fmaf(h[7],  C1.w, y3);
        h[8]  = fmaf(a[8],  h[8],  du * B2.x); y0 = fmaf(h[8],  C2.x, y0);
        h[9]  = fmaf(a[9],  h[9],  du * B2.y); y1 = fmaf(h[9],  C2.y, y1);
        h[10] = fmaf(a[10], h[10], du * B2.z); y2 = fmaf(h[10], C2.z, y2);
        h[11] = fmaf(a[11], h[11], du * B2.w); y3 = fmaf(h[11], C2.w, y3);
        h[12] = fmaf(a[12], h[12], du * B3.x); y0 = fmaf(h[12], C3.x, y0);
        h[13] = fmaf(a[13], h[13], du * B3.y); y1 = fmaf(h[13], C3.y, y1);
        h[14] = fmaf(a[14], h[14], du * B3.z); y2 = fmaf(h[14], C3.z, y2);
        h[15] = fmaf(a[15], h[15], du * B3.w); y3 = fmaf(h[15], C3.w, y3);
        const float yacc = (y0 + y1) + (y2 + y3);
        yb[(mbase + l) * DINNER + d] = f2bf(yacc * sz8[j]);
      }
    }
  } else {
    float Av[DSTATE];
#pragma unroll
    for (int n = 0; n < DSTATE; n++) Av[n] = -__expf(A_log[d * DSTATE + n]);
    for (int l = 0; l < CH; l++) {
      const float uv = bf2f(u16[(mbase + l) * DINNER + d]);
      const float zv = bf2f(zb[(mbase + l) * DINNER + d]);
      const float* Lr = &XL[l * 48];
      const float s = dot12(Lr, wr, b2);
      float dtv, e1;
      SOFTPLUS_E1(s, dtv, e1)
      (void)e1;
      const float du = dtv * uv;
      float yacc = Dv * uv;
#pragma unroll
      for (int n = 0; n < DSTATE; n++) {
        h[n] = fmaf(__expf(dtv * Av[n]), h[n], du * Lr[12 + n]);
        yacc = fmaf(h[n], Lr[28 + n], yacc);
      }
      yb[(mbase + l) * DINNER + d] = f2bf(yacc * silu_f(zv));
    }
  }
}

// out_proj: out[M][192] fp32 = yb[M][384] @ ow^T. BM=128 BN=64 BK=32, XCD swizzle.
__global__ __launch_bounds__(256) void gemm_out(const unsigned short* __restrict__ yb,
                                                const unsigned short* __restrict__ owb,
                                                float* __restrict__ out) {
  __shared__ unsigned short Als[128 * 40];
  __shared__ unsigned short Bls[64 * 40];
  const int tid = threadIdx.x;
  const int bid = blockIdx.y * 3 + blockIdx.x;        // 0..767
  const int lid = (bid & 7) * 96 + (bid >> 3);        // bijective (768%8==0)
  const int m0 = (lid / 3) * 128, n0 = (lid % 3) * 64;
  const int w = tid >> 6, l = tid & 63;
  const int wm = (w >> 1) * 64, wn = (w & 1) * 32;
  const int lr = l & 15, lk8 = (l >> 4) * 8;
  const int ar = tid >> 1, ag = (tid & 1) * 16;
  const int br = tid >> 2, bg = (tid & 3) * 8;
  const unsigned short* Ap = yb + (size_t)(m0 + ar) * DINNER + ag;
  const unsigned short* Wp = owb + (size_t)(n0 + br) * DINNER + bg;
  f32x4 acc[4][2];
#pragma unroll
  for (int i = 0; i < 4; i++)
#pragma unroll
    for (int j = 0; j < 2; j++) acc[i][j] = (f32x4){0.f, 0.f, 0.f, 0.f};
#pragma unroll
  for (int k0 = 0; k0 < DINNER; k0 += 32) {
    us8 a0 = *(const us8*)(Ap + k0);
    us8 a1 = *(const us8*)(Ap + k0 + 8);
    us8 bv = *(const us8*)(Wp + k0);
    __syncthreads();
    *(us8*)(&Als[ar * 40 + ag]) = a0;
    *(us8*)(&Als[ar * 40 + ag + 8]) = a1;
    *(us8*)(&Bls[br * 40 + bg]) = bv;
    __syncthreads();
    bf16x8 b0 = *(const bf16x8*)(&Bls[(wn + lr) * 40 + lk8]);
    bf16x8 b1 = *(const bf16x8*)(&Bls[(wn + 16 + lr) * 40 + lk8]);
#pragma unroll
    for (int fm = 0; fm < 4; fm++) {
      bf16x8 af = *(const bf16x8*)(&Als[(wm + fm * 16 + lr) * 40 + lk8]);
      acc[fm][0] = __builtin_amdgcn_mfma_f32_16x16x32_bf16(af, b0, acc[fm][0], 0, 0, 0);
      acc[fm][1] = __builtin_amdgcn_mfma_f32_16x16x32_bf16(af, b1, acc[fm][1], 0, 0, 0);
    }
  }
  const int r0 = (l >> 4) * 4;
#pragma unroll
  for (int fm = 0; fm < 4; fm++) {
    const size_t rowb = (size_t)(m0 + wm + fm * 16 + r0);
#pragma unroll
    for (int fn = 0; fn < 2; fn++) {
      const int col = n0 + wn + fn * 16 + lr;
#pragma unroll
      for (int r = 0; r < 4; r++)
        out[(rowb + r) * DMODEL + col] = acc[fm][fn][r];
    }
  }
}

extern "C" void kernel_launch(void* const* d_in, const int* in_sizes, int n_in,
                              void* d_out, int out_size, void* d_ws, size_t ws_size,
                              hipStream_t stream) {
  const float* hs   = (const float*)d_in[0];
  const float* in_w = (const float*)d_in[1];
  const float* cw   = (const float*)d_in[2];
  const float* cb   = (const float*)d_in[3];
  const float* xw   = (const float*)d_in[4];
  const float* dtw  = (const float*)d_in[5];
  const float* dtb  = (const float*)d_in[6];
  const float* alog = (const float*)d_in[7];
  const float* dsk  = (const float*)d_in[8];
  const float* ow   = (const float*)d_in[9];
  float* out = (float*)d_out;

  // ws layout (bytes), total ~135 MB
  char* ws = (char*)d_ws;
  unsigned short* xb  = (unsigned short*)(ws);                 // [M][384] bf16 25.17 MB (dead after xproj_conv)
  unsigned short* u16 = (unsigned short*)(ws + 25165824);      // [M][384] bf16 25.17 MB
  float* xdbl = (float*)(ws + 50331648);                       // [M][64]  fp32  8.39 MB
  float* Pbuf = (float*)(ws + 58720256);                       // 25.17 MB (becomes h0)
  float* Sbuf = (float*)(ws + 83886080);                       // 25.17 MB
  unsigned short* zb  = (unsigned short*)(ws + 109051904);     // [M][384] bf16 25.17 MB
  unsigned short* wb  = (unsigned short*)(ws + 134217728);     // [768][192] bf16 294912 B
  unsigned short* wxb = (unsigned short*)(ws + 134512640);     // [64][384]  bf16  49152 B
  unsigned short* owb = (unsigned short*)(ws + 134561792);     // [192][384] bf16 147456 B
  unsigned short* yb  = xb;   // part3 output over dead xb

  // 0. weight casts/pads
  prep_k<<<576, 256, 0, stream>>>(in_w, xw, ow, wb, wxb, owb);
  // 1. in_proj (bf16 MFMA, XCD-swizzled, bf16 x|z outputs)
  gemm_in<<<dim3(6, 256), 256, 0, stream>>>(hs, wb, xb, zb);
  // 2+3. x_proj with fused depthwise conv+SiLU (writes u16 through)
  xproj_conv<<<MTOT / 64, 256, 0, stream>>>(xb, cw, cb, wxb, xdbl, u16);
  // 4+5. chunked selective scan with fused dt_proj (grouped softplus pipeline)
  scan_part1<<<dim3(NC, BATCH), 384, 0, stream>>>(u16, xdbl, alog, dtw, dtb, Pbuf, Sbuf);
  scan_part2<<<(BATCH * DINNER * DSTATE) / 256, 256, 0, stream>>>(Pbuf, Sbuf);
  scan_part3<<<dim3(NC, BATCH), 384, 0, stream>>>(u16, xdbl, alog, dtw, dtb, dsk, zb, Pbuf, yb);
  // 6. out_proj (bf16 MFMA, XCD-swizzled)
  gemm_out<<<dim3(3, 256), 256, 0, stream>>>(yb, owb, out);
}

// Round 11
// 244.629 us; speedup vs baseline: 1.0968x; 1.0968x over previous
//
#include <hip/hip_runtime.h>
#include <cmath>

#define BATCH 8
#define SEQLEN 4096
#define DMODEL 192
#define DINNER 384
#define DSTATE 16
#define DTRANK 12
#define XSTR 64            // padded x_dbl row stride (44 real cols)
#define MTOT (BATCH*SEQLEN)
#define CH 32              // scan chunk length
#define NC (SEQLEN/CH)     // 128 chunks

typedef __bf16 bf16x8 __attribute__((ext_vector_type(8)));
typedef float f32x4 __attribute__((ext_vector_type(4)));
typedef unsigned short us8 __attribute__((ext_vector_type(8)));

__device__ __forceinline__ float fast_rcp(float x) { return __builtin_amdgcn_rcpf(x); }
__device__ __forceinline__ float silu_f(float x) { return x * fast_rcp(1.f + __expf(-x)); }
__device__ __forceinline__ unsigned short f2bf(float f) {
  unsigned u = __float_as_uint(f);
  return (unsigned short)((u + 0x7FFF + ((u >> 16) & 1)) >> 16);   // RNE
}
__device__ __forceinline__ float bf2f(unsigned short b) {
  return __uint_as_float(((unsigned)b) << 16);
}

// a[n] = e1^(n+1), binary tree, depth 4
#define POW16(a, e1)                                                        \
  a[0] = (e1); a[1] = (e1) * (e1); a[2] = a[1] * (e1); a[3] = a[1] * a[1];  \
  a[4] = a[3] * (e1); a[5] = a[3] * a[1]; a[6] = a[3] * a[2];               \
  a[7] = a[3] * a[3]; a[8] = a[7] * (e1); a[9] = a[7] * a[1];               \
  a[10] = a[7] * a[2]; a[11] = a[7] * a[3]; a[12] = a[7] * a[4];            \
  a[13] = a[7] * a[5]; a[14] = a[7] * a[6]; a[15] = a[7] * a[7];

// softplus pieces: dtv = softplus(s), e1 = exp(-dtv) = sigmoid(-s) via rcp
#define SOFTPLUS_E1(s, dtv, e1)                                             \
  { const float w_ = __expf(-fabsf(s));                                     \
    const float t_ = 1.f + w_;                                              \
    const float rq_ = fast_rcp(t_);                                         \
    dtv = fmaxf(s, 0.f) + __logf(t_);                                       \
    e1 = ((s) > 0.f) ? w_ * rq_ : rq_; }

// single prep kernel: cast in_proj_w, pad+cast x_proj_w, cast out_proj_w
__global__ __launch_bounds__(256) void prep_k(const float* __restrict__ in_w,
                                              const float* __restrict__ xw,
                                              const float* __restrict__ ow,
                                              unsigned short* __restrict__ wb,
                                              unsigned short* __restrict__ wxb,
                                              unsigned short* __restrict__ owb) {
  const int i = blockIdx.x * 256 + threadIdx.x;
  if (i < 768 * DMODEL) wb[i] = f2bf(in_w[i]);
  if (i < XSTR * DINNER) wxb[i] = (i < 44 * DINNER) ? f2bf(xw[i]) : (unsigned short)0;
  if (i < DMODEL * DINNER) owb[i] = f2bf(ow[i]);
}

// in_proj: [M][768] = hs[M][192] @ in_w^T. BM=128 BN=128 BK=32, XCD-chunked swizzle.
__global__ __launch_bounds__(256) void gemm_in(const float* __restrict__ hs,
                                               const unsigned short* __restrict__ wb,
                                               unsigned short* __restrict__ xb,
                                               unsigned short* __restrict__ zb) {
  __shared__ unsigned short Als[128 * 40];   // 80B rows
  __shared__ unsigned short Bls[128 * 40];
  const int tid = threadIdx.x;
  const int bid = blockIdx.y * 6 + blockIdx.x;        // 0..1535
  const int lid = (bid & 7) * 192 + (bid >> 3);       // bijective (1536%8==0)
  const int m0 = (lid / 6) * 128, n0 = (lid % 6) * 128;
  const int w = tid >> 6, l = tid & 63;
  const int wm = (w >> 1) * 64, wn = (w & 1) * 64;
  const int lr = l & 15, lk8 = (l >> 4) * 8;
  const int ar = tid >> 1, ag = (tid & 1) * 16;
  const float* Ap = hs + (size_t)(m0 + ar) * DMODEL + ag;
  const unsigned short* Wp = wb + (size_t)(n0 + ar) * DMODEL + ag;
  f32x4 acc[4][4];
#pragma unroll
  for (int i = 0; i < 4; i++)
#pragma unroll
    for (int j = 0; j < 4; j++) acc[i][j] = (f32x4){0.f, 0.f, 0.f, 0.f};
#pragma unroll
  for (int k0 = 0; k0 < DMODEL; k0 += 32) {
    float4 f0 = *(const float4*)(Ap + k0);
    float4 f1 = *(const float4*)(Ap + k0 + 4);
    float4 f2 = *(const float4*)(Ap + k0 + 8);
    float4 f3 = *(const float4*)(Ap + k0 + 12);
    us8 b0 = *(const us8*)(Wp + k0);
    us8 b1 = *(const us8*)(Wp + k0 + 8);
    us8 a0, a1;
    a0[0] = f2bf(f0.x); a0[1] = f2bf(f0.y); a0[2] = f2bf(f0.z); a0[3] = f2bf(f0.w);
    a0[4] = f2bf(f1.x); a0[5] = f2bf(f1.y); a0[6] = f2bf(f1.z); a0[7] = f2bf(f1.w);
    a1[0] = f2bf(f2.x); a1[1] = f2bf(f2.y); a1[2] = f2bf(f2.z); a1[3] = f2bf(f2.w);
    a1[4] = f2bf(f3.x); a1[5] = f2bf(f3.y); a1[6] = f2bf(f3.z); a1[7] = f2bf(f3.w);
    __syncthreads();
    *(us8*)(&Als[ar * 40 + ag]) = a0;
    *(us8*)(&Als[ar * 40 + ag + 8]) = a1;
    *(us8*)(&Bls[ar * 40 + ag]) = b0;
    *(us8*)(&Bls[ar * 40 + ag + 8]) = b1;
    __syncthreads();
    bf16x8 bfr[4];
#pragma unroll
    for (int fn = 0; fn < 4; fn++)
      bfr[fn] = *(const bf16x8*)(&Bls[(wn + fn * 16 + lr) * 40 + lk8]);
#pragma unroll
    for (int fm = 0; fm < 4; fm++) {
      bf16x8 af = *(const bf16x8*)(&Als[(wm + fm * 16 + lr) * 40 + lk8]);
#pragma unroll
      for (int fn = 0; fn < 4; fn++)
        acc[fm][fn] = __builtin_amdgcn_mfma_f32_16x16x32_bf16(af, bfr[fn], acc[fm][fn], 0, 0, 0);
    }
  }
  const int r0 = (l >> 4) * 4;   // C/D: col=lane&15, row=(lane>>4)*4+reg
  unsigned short* dst = (n0 < DINNER) ? xb : zb;
  const int cb0 = (n0 < DINNER) ? n0 : (n0 - DINNER);
#pragma unroll
  for (int fm = 0; fm < 4; fm++) {
    const size_t rowb = (size_t)(m0 + wm + fm * 16 + r0);
#pragma unroll
    for (int fn = 0; fn < 4; fn++) {
      const int col = cb0 + wn + fn * 16 + lr;
#pragma unroll
      for (int r = 0; r < 4; r++)
        dst[(rowb + r) * DINNER + col] = f2bf(acc[fm][fn][r]);
    }
  }
}

// x_proj with FUSED depthwise conv+SiLU in the A-staging (u16 written through).
__global__ __launch_bounds__(256) void xproj_conv(const unsigned short* __restrict__ xb,
                                                  const float* __restrict__ cw,
                                                  const float* __restrict__ cb,
                                                  const unsigned short* __restrict__ wxb,
                                                  float* __restrict__ xdbl,
                                                  unsigned short* __restrict__ u16) {
  __shared__ unsigned short Als[64 * 40];
  __shared__ unsigned short Bls[64 * 40];
  __shared__ float cws[DINNER * 4];   // [0..3*384) = cw, [3*384..) = cb
  const int tid = threadIdx.x;
  const int m0 = blockIdx.x * 64;
  for (int i = tid; i < DINNER * 4; i += 256)
    cws[i] = (i < DINNER * 3) ? cw[i] : cb[i - DINNER * 3];
  const int w = tid >> 6, l = tid & 63;
  const int wm = (w >> 1) * 32, wn = (w & 1) * 32;
  const int lr = l & 15, lk8 = (l >> 4) * 8;
  const int ar = tid >> 2, ag = (tid & 3) * 8;
  const int m = m0 + ar;
  const int lpos = m % SEQLEN;
  const bool hm = (lpos > 0), hp = (lpos < SEQLEN - 1);
  const unsigned short* Ap = xb + (size_t)m * DINNER + ag;
  const unsigned short* Wp = wxb + (size_t)ar * DINNER + ag;
  f32x4 acc[2][2];
#pragma unroll
  for (int i = 0; i < 2; i++)
#pragma unroll
    for (int j = 0; j < 2; j++) acc[i][j] = (f32x4){0.f, 0.f, 0.f, 0.f};
  __syncthreads();   // cws ready
#pragma unroll
  for (int k0 = 0; k0 < DINNER; k0 += 32) {
    us8 c0 = *(const us8*)(Ap + k0);
    us8 cm = c0, cp = c0;
    if (hm) cm = *(const us8*)(Ap + k0 - DINNER);
    if (hp) cp = *(const us8*)(Ap + k0 + DINNER);
    us8 b0 = *(const us8*)(Wp + k0);
    us8 a0;
#pragma unroll
    for (int j = 0; j < 8; j++) {
      const int col = ag + k0 + j;
      float s = cws[DINNER * 3 + col] + cws[col * 3 + 1] * bf2f(c0[j]);
      if (hm) s += cws[col * 3 + 0] * bf2f(cm[j]);
      if (hp) s += cws[col * 3 + 2] * bf2f(cp[j]);
      a0[j] = f2bf(silu_f(s));
    }
    *(us8*)(u16 + (size_t)m * DINNER + ag + k0) = a0;   // write-through for scans
    __syncthreads();
    *(us8*)(&Als[ar * 40 + ag]) = a0;
    *(us8*)(&Bls[ar * 40 + ag]) = b0;
    __syncthreads();
    bf16x8 bf0 = *(const bf16x8*)(&Bls[(wn + lr) * 40 + lk8]);
    bf16x8 bf1 = *(const bf16x8*)(&Bls[(wn + 16 + lr) * 40 + lk8]);
#pragma unroll
    for (int fm = 0; fm < 2; fm++) {
      bf16x8 af = *(const bf16x8*)(&Als[(wm + fm * 16 + lr) * 40 + lk8]);
      acc[fm][0] = __builtin_amdgcn_mfma_f32_16x16x32_bf16(af, bf0, acc[fm][0], 0, 0, 0);
      acc[fm][1] = __builtin_amdgcn_mfma_f32_16x16x32_bf16(af, bf1, acc[fm][1], 0, 0, 0);
    }
  }
  const int r0 = (l >> 4) * 4;
#pragma unroll
  for (int fm = 0; fm < 2; fm++) {
    const size_t rowb = (size_t)(m0 + wm + fm * 16 + r0);
#pragma unroll
    for (int fn = 0; fn < 2; fn++) {
      const int col = wn + fn * 16 + lr;
#pragma unroll
      for (int r = 0; r < 4; r++)
        xdbl[(rowb + r) * XSTR + col] = acc[fm][fn][r];
    }
  }
}

// dt_proj + softplus, hoisted OUT of the scan loops. 4 d/thread.
// Writes e1 = exp(-softplus(s)) = sigmoid(-s) in fp32 (powered to ^16 in scan;
// must be accurate) and dtv = softplus(s) in bf16 (enters only additively).
__global__ __launch_bounds__(256) void dtproj2_k(const float* __restrict__ xdbl,
                                                 const float* __restrict__ dtw,
                                                 const float* __restrict__ dtb,
                                                 float* __restrict__ e1f,
                                                 unsigned short* __restrict__ dtvb) {
  const int idx = blockIdx.x * 256 + threadIdx.x;
  const int q = (idx % 96) * 4;
  const size_t m = idx / 96;
  const float* xr = xdbl + m * XSTR;
  float xs[12];
  *(float4*)(xs) = *(const float4*)(xr);
  *(float4*)(xs + 4) = *(const float4*)(xr + 4);
  *(float4*)(xs + 8) = *(const float4*)(xr + 8);
  float4 eo;
  ushort4 dvo;
#pragma unroll
  for (int t = 0; t < 4; t++) {
    const int dd = q + t;
    const float* wr = dtw + dd * DTRANK;
    float s = 2.f * dtb[dd];
#pragma unroll
    for (int r = 0; r < DTRANK; r++) s = fmaf(xs[r], wr[r], s);
    float dtv, e1;
    SOFTPLUS_E1(s, dtv, e1)
    ((float*)&eo)[t] = e1;
    ((unsigned short*)&dvo)[t] = f2bf(dtv);
  }
  *(float4*)(e1f + m * DINNER + q) = eo;
  *(ushort4*)(dtvb + m * DINNER + q) = dvo;
}

// ---- chunked parallel scan, thread-per-(b,d), 16 states in registers ----
// Round-8 proven structure (simple loop + next-iter prefetch, no staging
// arrays -> no spill) but ZERO transcendentals in the serial loop: e1 and dtv
// are precomputed by dtproj2_k.
__global__ __launch_bounds__(384, 6) void scan_part1(const unsigned short* __restrict__ u16,
                                                     const float* __restrict__ e1f,
                                                     const unsigned short* __restrict__ dtvb,
                                                     const float* __restrict__ xdbl,
                                                     const float* __restrict__ A_log,
                                                     float* __restrict__ Pbuf,
                                                     float* __restrict__ Sbuf) {
  __shared__ float Bs[CH][DSTATE];
  const int d = threadIdx.x;
  const int c = blockIdx.x, b = blockIdx.y;
  const size_t mbase = (size_t)b * SEQLEN + (size_t)c * CH;
  if (d < CH * 4) {
    const int r = d >> 2, q = d & 3;
    float4 v = *(const float4*)(xdbl + (mbase + r) * XSTR + DTRANK + q * 4);
    float* dst = &Bs[r][q * 4];
    dst[0] = v.x; dst[1] = v.y; dst[2] = v.z; dst[3] = v.w;
  }
  bool fastp = true;
#pragma unroll
  for (int n = 0; n < DSTATE; n++)
    fastp = fastp && (fabsf(A_log[d * DSTATE + n] - __logf((float)(n + 1))) < 1e-5f);
  float h[DSTATE];
#pragma unroll
  for (int n = 0; n < DSTATE; n++) h[n] = 0.f;
  __syncthreads();
  float e1v = e1f[mbase * DINNER + d];
  float dtv = bf2f(dtvb[mbase * DINNER + d]);
  float uv  = bf2f(u16[mbase * DINNER + d]);
  float P[DSTATE];
  if (fastp) {
    float Pprod = 1.f;
    for (int l = 0; l < CH; l++) {
      const int lp = (l + 1 < CH) ? (l + 1) : l;
      const float e1n = e1f[(mbase + lp) * DINNER + d];
      const float dtn = bf2f(dtvb[(mbase + lp) * DINNER + d]);
      const float un  = bf2f(u16[(mbase + lp) * DINNER + d]);
      const float du = dtv * uv;
      Pprod *= e1v;
      float a[DSTATE];
      POW16(a, e1v)
#pragma unroll
      for (int n = 0; n < DSTATE; n++)
        h[n] = fmaf(a[n], h[n], du * Bs[l][n]);
      e1v = e1n; dtv = dtn; uv = un;
    }
    POW16(P, Pprod)
  } else {
    float Av[DSTATE];
#pragma unroll
    for (int n = 0; n < DSTATE; n++) Av[n] = -__expf(A_log[d * DSTATE + n]);
    float dtsum = 0.f;
    for (int l = 0; l < CH; l++) {
      const int lp = (l + 1 < CH) ? (l + 1) : l;
      const float dtn = bf2f(dtvb[(mbase + lp) * DINNER + d]);
      const float un  = bf2f(u16[(mbase + lp) * DINNER + d]);
      const float du = dtv * uv;
      dtsum += dtv;
#pragma unroll
      for (int n = 0; n < DSTATE; n++)
        h[n] = fmaf(__expf(dtv * Av[n]), h[n], du * Bs[l][n]);
      dtv = dtn; uv = un;
    }
#pragma unroll
    for (int n = 0; n < DSTATE; n++) P[n] = __expf(dtsum * Av[n]);
  }
  float* Pp = Pbuf + ((size_t)(b * NC + c) * DINNER + d) * DSTATE;
  float* Sp = Sbuf + ((size_t)(b * NC + c) * DINNER + d) * DSTATE;
#pragma unroll
  for (int q = 0; q < 4; q++) {
    float4 pv, sv;
    pv.x = P[q * 4 + 0]; pv.y = P[q * 4 + 1]; pv.z = P[q * 4 + 2]; pv.w = P[q * 4 + 3];
    sv.x = h[q * 4 + 0]; sv.y = h[q * 4 + 1]; sv.z = h[q * 4 + 2]; sv.w = h[q * 4 + 3];
    *(float4*)(Pp + q * 4) = pv;
    *(float4*)(Sp + q * 4) = sv;
  }
}

// Pass 2: combine across chunks, unroll x8 with batched loads.
__global__ __launch_bounds__(256) void scan_part2(float* __restrict__ Pbuf,
                                                  const float* __restrict__ Sbuf) {
  const int i = blockIdx.x * 256 + threadIdx.x;
  const int b = i / (DINNER * DSTATE);
  const int r = i % (DINNER * DSTATE);
  const size_t cs = DINNER * DSTATE;
  const size_t base = (size_t)b * NC * cs + r;
  float h = 0.f;
  for (int c0 = 0; c0 < NC; c0 += 8) {
    float pp[8], ss[8];
#pragma unroll
    for (int j = 0; j < 8; j++) {
      pp[j] = Pbuf[base + (size_t)(c0 + j) * cs];
      ss[j] = Sbuf[base + (size_t)(c0 + j) * cs];
    }
#pragma unroll
    for (int j = 0; j < 8; j++) {
      Pbuf[base + (size_t)(c0 + j) * cs] = h;
      h = fmaf(pp[j], h, ss[j]);
    }
  }
}

// Pass 3: re-run from h0; y = (h.C + D*u)*silu(z) -> bf16. Zero transcendentals
// in the fast-path loop except silu(z) (1 exp, independent of the h-chain).
__global__ __launch_bounds__(384, 6) void scan_part3(const unsigned short* __restrict__ u16,
                                                     const float* __restrict__ e1f,
                                                     const unsigned short* __restrict__ dtvb,
                                                     const float* __restrict__ xdbl,
                                                     const float* __restrict__ A_log,
                                                     const float* __restrict__ Dsk,
                                                     const unsigned short* __restrict__ zb,
                                                     const float* __restrict__ H0,
                                                     unsigned short* __restrict__ yb) {
  __shared__ float BC[CH][2 * DSTATE];   // [l][0..15]=B, [l][16..31]=C
  const int d = threadIdx.x;
  const int c = blockIdx.x, b = blockIdx.y;
  const size_t mbase = (size_t)b * SEQLEN + (size_t)c * CH;
  for (int i = d; i < CH * 8; i += 384) {
    const int r = i >> 3, q = i & 7;
    float4 v = *(const float4*)(xdbl + (mbase + r) * XSTR + DTRANK + q * 4);
    float* dst = &BC[r][q * 4];
    dst[0] = v.x; dst[1] = v.y; dst[2] = v.z; dst[3] = v.w;
  }
  bool fastp = true;
#pragma unroll
  for (int n = 0; n < DSTATE; n++)
    fastp = fastp && (fabsf(A_log[d * DSTATE + n] - __logf((float)(n + 1))) < 1e-5f);
  const float Dv = Dsk[d];
  float h[DSTATE];
  {
    const float* Hp = H0 + ((size_t)(b * NC + c) * DINNER + d) * DSTATE;
#pragma unroll
    for (int q = 0; q < 4; q++) {
      float4 v = *(const float4*)(Hp + q * 4);
      h[q * 4 + 0] = v.x; h[q * 4 + 1] = v.y; h[q * 4 + 2] = v.z; h[q * 4 + 3] = v.w;
    }
  }
  __syncthreads();
  float e1v = e1f[mbase * DINNER + d];
  float dtv = bf2f(dtvb[mbase * DINNER + d]);
  float uv  = bf2f(u16[mbase * DINNER + d]);
  float zv  = bf2f(zb[mbase * DINNER + d]);
  if (fastp) {
    for (int l = 0; l < CH; l++) {
      const int lp = (l + 1 < CH) ? (l + 1) : l;
      const float e1n = e1f[(mbase + lp) * DINNER + d];
      const float dtn = bf2f(dtvb[(mbase + lp) * DINNER + d]);
      const float un  = bf2f(u16[(mbase + lp) * DINNER + d]);
      const float zn  = bf2f(zb[(mbase + lp) * DINNER + d]);
      const float du = dtv * uv;
      const float sz = silu_f(zv);          // independent of h-chain
      float a[DSTATE];
      POW16(a, e1v)
      const float* Lr = &BC[l][0];
      float y0 = Dv * uv, y1 = 0.f, y2 = 0.f, y3 = 0.f;
#pragma unroll
      for (int n = 0; n < DSTATE; n += 4) {
        h[n + 0] = fmaf(a[n + 0], h[n + 0], du * Lr[n + 0]);
        h[n + 1] = fmaf(a[n + 1], h[n + 1], du * Lr[n + 1]);
        h[n + 2] = fmaf(a[n + 2], h[n + 2], du * Lr[n + 2]);
        h[n + 3] = fmaf(a[n + 3], h[n + 3], du * Lr[n + 3]);
        y0 = fmaf(h[n + 0], Lr[DSTATE + n + 0], y0);
        y1 = fmaf(h[n + 1], Lr[DSTATE + n + 1], y1);
        y2 = fmaf(h[n + 2], Lr[DSTATE + n + 2], y2);
        y3 = fmaf(h[n + 3], Lr[DSTATE + n + 3], y3);
      }
      const float yacc = (y0 + y1) + (y2 + y3);
      yb[(mbase + l) * DINNER + d] = f2bf(yacc * sz);
      e1v = e1n; dtv = dtn; uv = un; zv = zn;
    }
  } else {
    float Av[DSTATE];
#pragma unroll
    for (int n = 0; n < DSTATE; n++) Av[n] = -__expf(A_log[d * DSTATE + n]);
    for (int l = 0; l < CH; l++) {
      const int lp = (l + 1 < CH) ? (l + 1) : l;
      const float dtn = bf2f(dtvb[(mbase + lp) * DINNER + d]);
      const float un  = bf2f(u16[(mbase + lp) * DINNER + d]);
      const float zn  = bf2f(zb[(mbase + lp) * DINNER + d]);
      const float du = dtv * uv;
      float yacc = Dv * uv;
#pragma unroll
      for (int n = 0; n < DSTATE; n++) {
        h[n] = fmaf(__expf(dtv * Av[n]), h[n], du * BC[l][n]);
        yacc = fmaf(h[n], BC[l][DSTATE + n], yacc);
      }
      yb[(mbase + l) * DINNER + d] = f2bf(yacc * silu_f(zv));
      dtv = dtn; uv = un; zv = zn;
    }
  }
}

// out_proj: out[M][192] fp32 = yb[M][384] @ ow^T. BM=128 BN=64 BK=32, XCD swizzle.
__global__ __launch_bounds__(256) void gemm_out(const unsigned short* __restrict__ yb,
                                                const unsigned short* __restrict__ owb,
                                                float* __restrict__ out) {
  __shared__ unsigned short Als[128 * 40];
  __shared__ unsigned short Bls[64 * 40];
  const int tid = threadIdx.x;
  const int bid = blockIdx.y * 3 + blockIdx.x;        // 0..767
  const int lid = (bid & 7) * 96 + (bid >> 3);        // bijective (768%8==0)
  const int m0 = (lid / 3) * 128, n0 = (lid % 3) * 64;
  const int w = tid >> 6, l = tid & 63;
  const int wm = (w >> 1) * 64, wn = (w & 1) * 32;
  const int lr = l & 15, lk8 = (l >> 4) * 8;
  const int ar = tid >> 1, ag = (tid & 1) * 16;
  const int br = tid >> 2, bg = (tid & 3) * 8;
  const unsigned short* Ap = yb + (size_t)(m0 + ar) * DINNER + ag;
  const unsigned short* Wp = owb + (size_t)(n0 + br) * DINNER + bg;
  f32x4 acc[4][2];
#pragma unroll
  for (int i = 0; i < 4; i++)
#pragma unroll
    for (int j = 0; j < 2; j++) acc[i][j] = (f32x4){0.f, 0.f, 0.f, 0.f};
#pragma unroll
  for (int k0 = 0; k0 < DINNER; k0 += 32) {
    us8 a0 = *(const us8*)(Ap + k0);
    us8 a1 = *(const us8*)(Ap + k0 + 8);
    us8 bv = *(const us8*)(Wp + k0);
    __syncthreads();
    *(us8*)(&Als[ar * 40 + ag]) = a0;
    *(us8*)(&Als[ar * 40 + ag + 8]) = a1;
    *(us8*)(&Bls[br * 40 + bg]) = bv;
    __syncthreads();
    bf16x8 b0 = *(const bf16x8*)(&Bls[(wn + lr) * 40 + lk8]);
    bf16x8 b1 = *(const bf16x8*)(&Bls[(wn + 16 + lr) * 40 + lk8]);
#pragma unroll
    for (int fm = 0; fm < 4; fm++) {
      bf16x8 af = *(const bf16x8*)(&Als[(wm + fm * 16 + lr) * 40 + lk8]);
      acc[fm][0] = __builtin_amdgcn_mfma_f32_16x16x32_bf16(af, b0, acc[fm][0], 0, 0, 0);
      acc[fm][1] = __builtin_amdgcn_mfma_f32_16x16x32_bf16(af, b1, acc[fm][1], 0, 0, 0);
    }
  }
  const int r0 = (l >> 4) * 4;
#pragma unroll
  for (int fm = 0; fm < 4; fm++) {
    const size_t rowb = (size_t)(m0 + wm + fm * 16 + r0);
#pragma unroll
    for (int fn = 0; fn < 2; fn++) {
      const int col = n0 + wn + fn * 16 + lr;
#pragma unroll
      for (int r = 0; r < 4; r++)
        out[(rowb + r) * DMODEL + col] = acc[fm][fn][r];
    }
  }
}

extern "C" void kernel_launch(void* const* d_in, const int* in_sizes, int n_in,
                              void* d_out, int out_size, void* d_ws, size_t ws_size,
                              hipStream_t stream) {
  const float* hs   = (const float*)d_in[0];
  const float* in_w = (const float*)d_in[1];
  const float* cw   = (const float*)d_in[2];
  const float* cb   = (const float*)d_in[3];
  const float* xw   = (const float*)d_in[4];
  const float* dtw  = (const float*)d_in[5];
  const float* dtb  = (const float*)d_in[6];
  const float* alog = (const float*)d_in[7];
  const float* dsk  = (const float*)d_in[8];
  const float* ow   = (const float*)d_in[9];
  float* out = (float*)d_out;

  // ws layout (bytes), total ~210 MB
  char* ws = (char*)d_ws;
  unsigned short* xb  = (unsigned short*)(ws);                 // [M][384] bf16 25.17 MB (dead after xproj_conv)
  unsigned short* u16 = (unsigned short*)(ws + 25165824);      // [M][384] bf16 25.17 MB
  float* xdbl = (float*)(ws + 50331648);                       // [M][64]  fp32  8.39 MB
  float* Pbuf = (float*)(ws + 58720256);                       // 25.17 MB (becomes h0)
  float* Sbuf = (float*)(ws + 83886080);                       // 25.17 MB
  unsigned short* zb  = (unsigned short*)(ws + 109051904);     // [M][384] bf16 25.17 MB
  float* e1f = (float*)(ws + 134217728);                       // [M][384] fp32 50.33 MB
  unsigned short* dtvb = (unsigned short*)(ws + 184549376);    // [M][384] bf16 25.17 MB
  unsigned short* wb  = (unsigned short*)(ws + 209715200);     // [768][192] bf16 294912 B
  unsigned short* wxb = (unsigned short*)(ws + 210010112);     // [64][384]  bf16  49152 B
  unsigned short* owb = (unsigned short*)(ws + 210059264);     // [192][384] bf16 147456 B
  unsigned short* yb  = xb;   // part3 output over dead xb

  // 0. weight casts/pads
  prep_k<<<576, 256, 0, stream>>>(in_w, xw, ow, wb, wxb, owb);
  // 1. in_proj (bf16 MFMA, XCD-swizzled, bf16 x|z outputs)
  gemm_in<<<dim3(6, 256), 256, 0, stream>>>(hs, wb, xb, zb);
  // 2+3. x_proj with fused depthwise conv+SiLU (writes u16 through)
  xproj_conv<<<MTOT / 64, 256, 0, stream>>>(xb, cw, cb, wxb, xdbl, u16);
  // 4. dt_proj + softplus hoisted out of scans: e1 fp32, dtv bf16
  dtproj2_k<<<(MTOT * 96) / 256, 256, 0, stream>>>(xdbl, dtw, dtb, e1f, dtvb);
  // 5. chunked selective scan (transcendental-free serial loops)
  scan_part1<<<dim3(NC, BATCH), 384, 0, stream>>>(u16, e1f, dtvb, xdbl, alog, Pbuf, Sbuf);
  scan_part2<<<(BATCH * DINNER * DSTATE) / 256, 256, 0, stream>>>(Pbuf, Sbuf);
  scan_part3<<<dim3(NC, BATCH), 384, 0, stream>>>(u16, e1f, dtvb, xdbl, alog, dsk, zb, Pbuf, yb);
  // 6. out_proj (bf16 MFMA, XCD-swizzled)
  gemm_out<<<dim3(3, 256), 256, 0, stream>>>(yb, owb, out);
}